// Round 1
// baseline (1340.468 us; speedup 1.0000x reference)
//
#include <hip/hip_runtime.h>
#include <hip/hip_bf16.h>

typedef unsigned short u16;
typedef __attribute__((ext_vector_type(4))) float f32x4;
typedef __attribute__((ext_vector_type(8))) short s16x8;
typedef __attribute__((ext_vector_type(4))) short s16x4;
typedef __attribute__((ext_vector_type(8))) __bf16 bf16x8;

#define NTOK 4096
#define DMODEL 1024
#define DFF 4096
#define NH 16
#define TSEQ 1024

// ---------- helpers ----------

__device__ __forceinline__ u16 f2bu(float f) {
  // round-to-nearest-even f32 -> bf16 (finite values only)
  unsigned int u = __float_as_uint(f);
  unsigned int r = (u + 0x7FFFu + ((u >> 16) & 1u)) >> 16;
  return (u16)r;
}

__device__ __forceinline__ f32x4 mfma16(s16x8 a, s16x8 b, f32x4 c) {
  return __builtin_amdgcn_mfma_f32_16x16x32_bf16((bf16x8)a, (bf16x8)b, c, 0, 0, 0);
}

__device__ __forceinline__ void gload16(const u16* g, u16* l) {
  __builtin_amdgcn_global_load_lds(
      (const __attribute__((address_space(1))) unsigned int*)g,
      (__attribute__((address_space(3))) unsigned int*)l, 16, 0, 0);
}

// fragment: elements k = lhi*4 + (i&3) + 16*(i>>2), contiguous 4 + contiguous 4 at +16
__device__ __forceinline__ s16x8 ldfrag(const u16* p) {
  s16x4 lo = *(const s16x4*)p;
  s16x4 hi = *(const s16x4*)(p + 16);
  s16x8 r;
  r[0] = lo[0]; r[1] = lo[1]; r[2] = lo[2]; r[3] = lo[3];
  r[4] = hi[0]; r[5] = hi[1]; r[6] = hi[2]; r[7] = hi[3];
  return r;
}

// ---------- fp32 -> bf16 convert (n multiple of 1024) ----------

__global__ __launch_bounds__(256) void f2b_kernel(const float* __restrict__ src,
                                                  u16* __restrict__ dst) {
  size_t i = ((size_t)blockIdx.x * 256 + threadIdx.x) * 4;
  float4 v = *(const float4*)(src + i);
  ushort4 o = make_ushort4(f2bu(v.x), f2bu(v.y), f2bu(v.z), f2bu(v.w));
  *(ushort4*)(dst + i) = o;
}

// ---------- LayerNorm (exact ref semantics: std = sqrt(ss/1023), /(std+eps)) ----------

__global__ __launch_bounds__(256) void ln_kernel(const float* __restrict__ x,
                                                 const float* __restrict__ w,
                                                 const float* __restrict__ b,
                                                 u16* __restrict__ out) {
  int row = blockIdx.x;
  int t = threadIdx.x;
  const float* xr = x + (size_t)row * DMODEL;
  float4 v = *(const float4*)(xr + t * 4);
  float s = v.x + v.y + v.z + v.w;
#pragma unroll
  for (int off = 1; off < 64; off <<= 1) s += __shfl_xor(s, off);
  __shared__ float red[8];
  int wid = t >> 6, lane = t & 63;
  if (lane == 0) red[wid] = s;
  __syncthreads();
  float mean = (red[0] + red[1] + red[2] + red[3]) * (1.0f / 1024.0f);
  float dx = v.x - mean, dy = v.y - mean, dz = v.z - mean, dw = v.w - mean;
  float ss = dx * dx + dy * dy + dz * dz + dw * dw;
#pragma unroll
  for (int off = 1; off < 64; off <<= 1) ss += __shfl_xor(ss, off);
  if (lane == 0) red[4 + wid] = ss;
  __syncthreads();
  float sst = red[4] + red[5] + red[6] + red[7];
  float inv = 1.0f / (sqrtf(sst / 1023.0f) + 1e-6f);
  float4 wv = *(const float4*)(w + t * 4);
  float4 bv = *(const float4*)(b + t * 4);
  ushort4 o = make_ushort4(f2bu(wv.x * dx * inv + bv.x), f2bu(wv.y * dy * inv + bv.y),
                           f2bu(wv.z * dz * inv + bv.z), f2bu(wv.w * dw * inv + bv.w));
  *(ushort4*)(out + (size_t)row * DMODEL + t * 4) = o;
}

// ---------- GEMM: C[M,N] = A[M,K] * W[N,K]^T (+bias, +resid, relu) ----------
// MODE 0: fp32 out [M,N];  MODE 1: bf16 out [M,N];  MODE 2: bf16 out permuted [B,H,T,dk]

template <int MODE, bool RELU>
__global__ __launch_bounds__(256) void gemm_bt(const u16* __restrict__ A,
                                               const u16* __restrict__ W,
                                               const float* __restrict__ bias,
                                               const float* resid, void* outp,
                                               int M, int N, int K) {
  __shared__ u16 As[128 * 32];
  __shared__ u16 Bs[128 * 32];
  const int tid = threadIdx.x;
  const int m0 = blockIdx.y * 128, n0 = blockIdx.x * 128;
  const int wid = tid >> 6, lane = tid & 63;
  const int wr = wid >> 1, wc = wid & 1;
  const int lhi = lane >> 4, llo = lane & 15;
  f32x4 acc[4][4] = {};
  const int e0 = tid * 8, e1 = e0 + 2048;
  const int r0 = e0 >> 5, c0 = e0 & 31;

  for (int k0 = 0; k0 < K; k0 += 32) {
    __syncthreads();
    gload16(A + (size_t)(m0 + r0) * K + k0 + c0, As + e0);
    gload16(A + (size_t)(m0 + r0 + 64) * K + k0 + c0, As + e1);
    gload16(W + (size_t)(n0 + r0) * K + k0 + c0, Bs + e0);
    gload16(W + (size_t)(n0 + r0 + 64) * K + k0 + c0, Bs + e1);
    __syncthreads();
    s16x8 af[4], bfr[4];
#pragma unroll
    for (int f = 0; f < 4; f++) {
      af[f] = ldfrag(As + (wr * 64 + f * 16 + llo) * 32 + lhi * 4);
      bfr[f] = ldfrag(Bs + (wc * 64 + f * 16 + llo) * 32 + lhi * 4);
    }
#pragma unroll
    for (int fm = 0; fm < 4; fm++)
#pragma unroll
      for (int fn = 0; fn < 4; fn++)
        acc[fm][fn] = mfma16(af[fm], bfr[fn], acc[fm][fn]);
  }

#pragma unroll
  for (int fm = 0; fm < 4; fm++) {
#pragma unroll
    for (int fn = 0; fn < 4; fn++) {
      int c = n0 + wc * 64 + fn * 16 + llo;
      float bv = bias[c];
#pragma unroll
      for (int i = 0; i < 4; i++) {
        int r = m0 + wr * 64 + fm * 16 + lhi * 4 + i;
        float v = acc[fm][fn][i] + bv;
        if (resid) v += resid[(size_t)r * N + c];
        if (RELU) v = fmaxf(v, 0.0f);
        if (MODE == 0) {
          ((float*)outp)[(size_t)r * N + c] = v;
        } else if (MODE == 1) {
          ((u16*)outp)[(size_t)r * N + c] = f2bu(v);
        } else {
          int bb = r >> 10, t = r & 1023, hh = c >> 6, d = c & 63;
          ((u16*)outp)[(((size_t)(bb * NH + hh)) * TSEQ + t) * 64 + d] = f2bu(v);
        }
      }
    }
  }
}

// ---------- flash attention, swapped-QK^T; Q,K,V bf16 [B,H,T,64]; out bf16 [tok, DMODEL] ----------

template <bool CAUSAL>
__global__ __launch_bounds__(256) void attn_kernel(const u16* __restrict__ Qg,
                                                   const u16* __restrict__ Kg,
                                                   const u16* __restrict__ Vg,
                                                   u16* __restrict__ Og) {
  const int S = TSEQ;
  int bh = blockIdx.y;
  int b = bh >> 4, h = bh & 15;
  int q0 = blockIdx.x * 64;
  int tid = threadIdx.x, wid = tid >> 6, lane = tid & 63;
  int lhi = lane >> 4, llo = lane & 15;
  __shared__ u16 Ks[64 * 64];   // [kv][dk]
  __shared__ u16 Vs[64 * 64];   // transposed: [dk][kv]

  int qrow = q0 + wid * 16 + llo;
  const u16* qp = Qg + ((size_t)bh * TSEQ + qrow) * 64;
  s16x8 qf[2];
  qf[0] = ldfrag(qp + lhi * 4);
  qf[1] = ldfrag(qp + 32 + lhi * 4);

  f32x4 oacc[4] = {};
  float mrun = -3.0e38f, lrun = 0.0f;
  const size_t kvbase = (size_t)bh * S * 64;
  const int s_end = CAUSAL ? (q0 + 64) : S;

  for (int s0 = 0; s0 < s_end; s0 += 64) {
    __syncthreads();
    // stage K tile (linear, async direct-to-LDS)
    {
      int e0 = tid * 8, e1 = e0 + 2048;
      gload16(Kg + kvbase + (size_t)s0 * 64 + e0, Ks + e0);
      gload16(Kg + kvbase + (size_t)s0 * 64 + e1, Ks + e1);
    }
    // stage V transposed
#pragma unroll
    for (int cchunk = 0; cchunk < 2; cchunk++) {
      int cc = cchunk * 256 + tid;
      int kv = cc >> 3, d0 = (cc & 7) * 8;
      s16x8 v = *(const s16x8*)(Vg + kvbase + (size_t)(s0 + kv) * 64 + d0);
#pragma unroll
      for (int j = 0; j < 8; j++) Vs[(d0 + j) * 64 + kv] = (u16)v[j];
    }
    __syncthreads();

    // S^T = K * Q^T : sacc[g][i] = S[q=llo][kv = g*16 + lhi*4 + i]
    f32x4 sacc[4] = {};
#pragma unroll
    for (int g = 0; g < 4; g++) {
      const u16* kp = Ks + (g * 16 + llo) * 64 + lhi * 4;
      sacc[g] = mfma16(ldfrag(kp), qf[0], sacc[g]);
      sacc[g] = mfma16(ldfrag(kp + 32), qf[1], sacc[g]);
    }

    // online softmax (per-lane q = llo; partners at lane^16, lane^32)
    float sv[16];
    float pmax = -3.0e38f;
#pragma unroll
    for (int g = 0; g < 4; g++)
#pragma unroll
      for (int i = 0; i < 4; i++) {
        float sc = sacc[g][i] * 0.125f;
        if (CAUSAL) {
          int kv = s0 + g * 16 + lhi * 4 + i;
          if (kv > qrow) sc = -1.0e9f;
        }
        sv[g * 4 + i] = sc;
        pmax = fmaxf(pmax, sc);
      }
    pmax = fmaxf(pmax, __shfl_xor(pmax, 16));
    pmax = fmaxf(pmax, __shfl_xor(pmax, 32));
    float mnew = fmaxf(mrun, pmax);
    float alpha = __expf(mrun - mnew);
    float pv[16];
    float ls = 0.0f;
#pragma unroll
    for (int j = 0; j < 16; j++) {
      float p = __expf(sv[j] - mnew);
      pv[j] = p;
      ls += p;
    }
    ls += __shfl_xor(ls, 16);
    ls += __shfl_xor(ls, 32);
    lrun = lrun * alpha + ls;
    mrun = mnew;
#pragma unroll
    for (int g = 0; g < 4; g++) {
      oacc[g][0] *= alpha; oacc[g][1] *= alpha;
      oacc[g][2] *= alpha; oacc[g][3] *= alpha;
    }
    // P fragments for PV (B-operand layout == S^T C-layout)
    s16x8 pf[2];
#pragma unroll
    for (int kk = 0; kk < 2; kk++)
#pragma unroll
      for (int i2 = 0; i2 < 8; i2++)
        pf[kk][i2] = (short)f2bu(pv[(kk * 2 + (i2 >> 2)) * 4 + (i2 & 3)]);
    // O^T += V^T * P^T : oacc[dg][i] = O[q=llo][d = dg*16 + lhi*4 + i]
#pragma unroll
    for (int dg = 0; dg < 4; dg++) {
      const u16* vp = Vs + (dg * 16 + llo) * 64 + lhi * 4;
      oacc[dg] = mfma16(ldfrag(vp), pf[0], oacc[dg]);
      oacc[dg] = mfma16(ldfrag(vp + 32), pf[1], oacc[dg]);
    }
  }

  float inv = 1.0f / lrun;
  u16* orow = Og + (size_t)(b * TSEQ + qrow) * DMODEL + h * 64;
#pragma unroll
  for (int dg = 0; dg < 4; dg++)
#pragma unroll
    for (int i = 0; i < 4; i++)
      orow[dg * 16 + lhi * 4 + i] = f2bu(oacc[dg][i] * inv);
}

// ---------- launch ----------

extern "C" void kernel_launch(void* const* d_in, const int* in_sizes, int n_in,
                              void* d_out, int out_size, void* d_ws, size_t ws_size,
                              hipStream_t stream) {
  const float* x      = (const float*)d_in[0];
  const float* memory = (const float*)d_in[1];
  const float* sa_wq = (const float*)d_in[4];  const float* sa_bq = (const float*)d_in[5];
  const float* sa_wk = (const float*)d_in[6];  const float* sa_bk = (const float*)d_in[7];
  const float* sa_wv = (const float*)d_in[8];  const float* sa_bv = (const float*)d_in[9];
  const float* sa_wo = (const float*)d_in[10]; const float* sa_bo = (const float*)d_in[11];
  const float* ca_wq = (const float*)d_in[12]; const float* ca_bq = (const float*)d_in[13];
  const float* ca_wk = (const float*)d_in[14]; const float* ca_bk = (const float*)d_in[15];
  const float* ca_wv = (const float*)d_in[16]; const float* ca_bv = (const float*)d_in[17];
  const float* ca_wo = (const float*)d_in[18]; const float* ca_bo = (const float*)d_in[19];
  const float* ff_w1 = (const float*)d_in[20]; const float* ff_b1 = (const float*)d_in[21];
  const float* ff_w2 = (const float*)d_in[22]; const float* ff_b2 = (const float*)d_in[23];
  const float* ln1_w = (const float*)d_in[24]; const float* ln1_b = (const float*)d_in[25];
  const float* ln2_w = (const float*)d_in[26]; const float* ln2_b = (const float*)d_in[27];
  const float* ln3_w = (const float*)d_in[28]; const float* ln3_b = (const float*)d_in[29];
  float* out = (float*)d_out;

  char* ws = (char*)d_ws;
  const size_t MB = 1u << 20;
  u16* h_bf   = (u16*)(ws + 0 * MB);    // 8MB  LN output (bf16)
  u16* mem_bf = (u16*)(ws + 8 * MB);    // 8MB
  u16* qb     = (u16*)(ws + 16 * MB);   // 8MB  [B,H,T,64]
  u16* kb     = (u16*)(ws + 24 * MB);   // 8MB
  u16* vb     = (u16*)(ws + 32 * MB);   // 8MB
  u16* attnb  = (u16*)(ws + 40 * MB);   // 8MB  [tok, DMODEL]
  u16* ffmid  = (u16*)(ws + 48 * MB);   // 32MB [tok, DFF]
  u16* w_sq   = (u16*)(ws + 80 * MB);   // 2MB each
  u16* w_sk   = (u16*)(ws + 82 * MB);
  u16* w_sv   = (u16*)(ws + 84 * MB);
  u16* w_so   = (u16*)(ws + 86 * MB);
  u16* w_cq   = (u16*)(ws + 88 * MB);
  u16* w_ck   = (u16*)(ws + 90 * MB);
  u16* w_cv   = (u16*)(ws + 92 * MB);
  u16* w_co   = (u16*)(ws + 94 * MB);
  u16* w_f1   = (u16*)(ws + 96 * MB);   // 8MB
  u16* w_f2   = (u16*)(ws + 104 * MB);  // 8MB

  // weight + memory conversions
  f2b_kernel<<<1024, 256, 0, stream>>>(sa_wq, w_sq);
  f2b_kernel<<<1024, 256, 0, stream>>>(sa_wk, w_sk);
  f2b_kernel<<<1024, 256, 0, stream>>>(sa_wv, w_sv);
  f2b_kernel<<<1024, 256, 0, stream>>>(sa_wo, w_so);
  f2b_kernel<<<1024, 256, 0, stream>>>(ca_wq, w_cq);
  f2b_kernel<<<1024, 256, 0, stream>>>(ca_wk, w_ck);
  f2b_kernel<<<1024, 256, 0, stream>>>(ca_wv, w_cv);
  f2b_kernel<<<1024, 256, 0, stream>>>(ca_wo, w_co);
  f2b_kernel<<<4096, 256, 0, stream>>>(ff_w1, w_f1);
  f2b_kernel<<<4096, 256, 0, stream>>>(ff_w2, w_f2);
  f2b_kernel<<<4096, 256, 0, stream>>>(memory, mem_bf);

  dim3 g1024(8, 32);   // N=1024 tiles
  dim3 g4096(32, 32);  // N=4096 tiles
  dim3 gattn(16, 64);

  // ---- self-attention block ----
  ln_kernel<<<4096, 256, 0, stream>>>(x, ln1_w, ln1_b, h_bf);
  gemm_bt<2, false><<<g1024, 256, 0, stream>>>(h_bf, w_sq, sa_bq, nullptr, qb, NTOK, DMODEL, DMODEL);
  gemm_bt<2, false><<<g1024, 256, 0, stream>>>(h_bf, w_sk, sa_bk, nullptr, kb, NTOK, DMODEL, DMODEL);
  gemm_bt<2, false><<<g1024, 256, 0, stream>>>(h_bf, w_sv, sa_bv, nullptr, vb, NTOK, DMODEL, DMODEL);
  attn_kernel<true><<<gattn, 256, 0, stream>>>(qb, kb, vb, attnb);
  gemm_bt<0, false><<<g1024, 256, 0, stream>>>(attnb, w_so, sa_bo, x, out, NTOK, DMODEL, DMODEL);

  // ---- cross-attention block ----
  ln_kernel<<<4096, 256, 0, stream>>>(out, ln2_w, ln2_b, h_bf);
  gemm_bt<2, false><<<g1024, 256, 0, stream>>>(h_bf, w_cq, ca_bq, nullptr, qb, NTOK, DMODEL, DMODEL);
  gemm_bt<2, false><<<g1024, 256, 0, stream>>>(mem_bf, w_ck, ca_bk, nullptr, kb, NTOK, DMODEL, DMODEL);
  gemm_bt<2, false><<<g1024, 256, 0, stream>>>(mem_bf, w_cv, ca_bv, nullptr, vb, NTOK, DMODEL, DMODEL);
  attn_kernel<false><<<gattn, 256, 0, stream>>>(qb, kb, vb, attnb);
  gemm_bt<0, false><<<g1024, 256, 0, stream>>>(attnb, w_co, ca_bo, out, out, NTOK, DMODEL, DMODEL);

  // ---- FFN block ----
  ln_kernel<<<4096, 256, 0, stream>>>(out, ln3_w, ln3_b, h_bf);
  gemm_bt<1, true><<<g4096, 256, 0, stream>>>(h_bf, w_f1, ff_b1, nullptr, ffmid, NTOK, DFF, DMODEL);
  gemm_bt<0, false><<<g1024, 256, 0, stream>>>(ffmid, w_f2, ff_b2, out, out, NTOK, DMODEL, DFF);

  (void)in_sizes; (void)n_in; (void)out_size; (void)d_ws; (void)ws_size;
}

// Round 2
// 435.504 us; speedup vs baseline: 3.0780x; 3.0780x over previous
//
#include <hip/hip_runtime.h>
#include <hip/hip_bf16.h>

typedef unsigned short u16;
typedef __attribute__((ext_vector_type(4))) float f32x4;
typedef __attribute__((ext_vector_type(8))) short s16x8;
typedef __attribute__((ext_vector_type(4))) short s16x4;
typedef __attribute__((ext_vector_type(8))) __bf16 bf16x8;

#define NTOK 4096
#define DMODEL 1024
#define DFF 4096
#define NH 16
#define TSEQ 1024

// ---------- helpers ----------

__device__ __forceinline__ u16 f2bu(float f) {
  unsigned int u = __float_as_uint(f);
  unsigned int r = (u + 0x7FFFu + ((u >> 16) & 1u)) >> 16;
  return (u16)r;
}

__device__ __forceinline__ f32x4 mfma16(s16x8 a, s16x8 b, f32x4 c) {
  return __builtin_amdgcn_mfma_f32_16x16x32_bf16((bf16x8)a, (bf16x8)b, c, 0, 0, 0);
}

__device__ __forceinline__ void gload16(const u16* g, u16* l) {
  __builtin_amdgcn_global_load_lds(
      (const __attribute__((address_space(1))) unsigned int*)g,
      (__attribute__((address_space(3))) unsigned int*)l, 16, 0, 0);
}

// natural-layout fragment from global: 4 elems at p, 4 at p+16
__device__ __forceinline__ s16x8 ldfrag(const u16* p) {
  s16x4 lo = *(const s16x4*)p;
  s16x4 hi = *(const s16x4*)(p + 16);
  s16x8 r;
  r[0] = lo[0]; r[1] = lo[1]; r[2] = lo[2]; r[3] = lo[3];
  r[4] = hi[0]; r[5] = hi[1]; r[6] = hi[2]; r[7] = hi[3];
  return r;
}

// natural-layout fragment from a swizzled 64-elem-row LDS tile.
// eoff: element offset within row for the low half (high half at eoff+16).
// swizzle: 16B chunk index XOR (row&7).
__device__ __forceinline__ s16x8 ld8s(const u16* t, int row, int eoff) {
  int rx = row & 7;
  const u16* p1 = t + row * 64 + ((((eoff >> 3) ^ rx) << 3) | (eoff & 7));
  const u16* p2 = t + row * 64 + (((((eoff + 16) >> 3) ^ rx) << 3) | (eoff & 7));
  s16x4 lo = *(const s16x4*)p1;
  s16x4 hi = *(const s16x4*)p2;
  s16x8 r;
  r[0] = lo[0]; r[1] = lo[1]; r[2] = lo[2]; r[3] = lo[3];
  r[4] = hi[0]; r[5] = hi[1]; r[6] = hi[2]; r[7] = hi[3];
  return r;
}

// k-permuted (contiguous 16B) fragment from swizzled 64-elem-row LDS tile
__device__ __forceinline__ s16x8 ld16s(const u16* t, int row, int ch) {
  return *(const s16x8*)(t + row * 64 + ((ch ^ (row & 7)) << 3));
}

// ---------- fp32 -> bf16 convert ----------

__global__ __launch_bounds__(256) void f2b_kernel(const float* __restrict__ src,
                                                  u16* __restrict__ dst) {
  size_t i = ((size_t)blockIdx.x * 256 + threadIdx.x) * 4;
  float4 v = *(const float4*)(src + i);
  ushort4 o = make_ushort4(f2bu(v.x), f2bu(v.y), f2bu(v.z), f2bu(v.w));
  *(ushort4*)(dst + i) = o;
}

// ---------- LayerNorm ----------

__global__ __launch_bounds__(256) void ln_kernel(const float* __restrict__ x,
                                                 const float* __restrict__ w,
                                                 const float* __restrict__ b,
                                                 u16* __restrict__ out) {
  int row = blockIdx.x;
  int t = threadIdx.x;
  const float* xr = x + (size_t)row * DMODEL;
  float4 v = *(const float4*)(xr + t * 4);
  float s = v.x + v.y + v.z + v.w;
#pragma unroll
  for (int off = 1; off < 64; off <<= 1) s += __shfl_xor(s, off);
  __shared__ float red[8];
  int wid = t >> 6, lane = t & 63;
  if (lane == 0) red[wid] = s;
  __syncthreads();
  float mean = (red[0] + red[1] + red[2] + red[3]) * (1.0f / 1024.0f);
  float dx = v.x - mean, dy = v.y - mean, dz = v.z - mean, dw = v.w - mean;
  float ss = dx * dx + dy * dy + dz * dz + dw * dw;
#pragma unroll
  for (int off = 1; off < 64; off <<= 1) ss += __shfl_xor(ss, off);
  if (lane == 0) red[4 + wid] = ss;
  __syncthreads();
  float sst = red[4] + red[5] + red[6] + red[7];
  float inv = 1.0f / (sqrtf(sst / 1023.0f) + 1e-6f);
  float4 wv = *(const float4*)(w + t * 4);
  float4 bv = *(const float4*)(b + t * 4);
  ushort4 o = make_ushort4(f2bu(wv.x * dx * inv + bv.x), f2bu(wv.y * dy * inv + bv.y),
                           f2bu(wv.z * dz * inv + bv.z), f2bu(wv.w * dw * inv + bv.w));
  *(ushort4*)(out + (size_t)row * DMODEL + t * 4) = o;
}

// ---------- GEMM: C[M,N] = A[M,K] * W[N,K]^T (+bias, +resid, relu) ----------
// 512 threads, 8 waves (2 M x 4 N), 128x128 tile, BK=64, double-buffered LDS,
// 2-phase prefetch, XOR-swizzled LDS, k-permuted contiguous-16B fragments.
// MODE 0: fp32 out [M,N]; MODE 1: bf16 out [M,N]; MODE 2: bf16 out [B,H,T,dk]

template <int MODE, bool RELU>
__global__ __launch_bounds__(512) void gemm_bt(const u16* __restrict__ A,
                                               const u16* __restrict__ W,
                                               const float* __restrict__ bias,
                                               const float* resid, void* outp,
                                               int M, int N, int K) {
  __shared__ u16 As[2][128 * 64];
  __shared__ u16 Bs[2][128 * 64];
  const int tid = threadIdx.x;
  const int m0 = blockIdx.y * 128, n0 = blockIdx.x * 128;
  const int wid = tid >> 6, lane = tid & 63;
  const int wr = wid >> 2, wc = wid & 3;
  const int lhi = lane >> 4, llo = lane & 15;
  f32x4 acc[4][2] = {};
  // staging: thread covers (row sr, chunk sc) of each 64-row half
  const int sr = tid >> 3, sc = tid & 7;
  const int srcoff = (sc ^ (sr & 7)) << 3;  // pre-swizzled source chunk

  auto stage = [&](int kk, int buf) {
    const u16* Ap = A + (size_t)(m0 + sr) * K + kk + srcoff;
    gload16(Ap, &As[buf][tid * 8]);
    gload16(Ap + (size_t)64 * K, &As[buf][4096 + tid * 8]);
    const u16* Wp = W + (size_t)(n0 + sr) * K + kk + srcoff;
    gload16(Wp, &Bs[buf][tid * 8]);
    gload16(Wp + (size_t)64 * K, &Bs[buf][4096 + tid * 8]);
  };

  stage(0, 0);
  __syncthreads();

  for (int k0 = 0; k0 < K; k0 += 64) {
    int cur = (k0 >> 6) & 1;
    if (k0 + 64 < K) stage(k0 + 64, cur ^ 1);
#pragma unroll
    for (int ks8 = 0; ks8 < 8; ks8 += 4) {
      s16x8 af[4], bfr[2];
#pragma unroll
      for (int f = 0; f < 4; f++) af[f] = ld16s(&As[cur][0], wr * 64 + f * 16 + llo, ks8 + lhi);
#pragma unroll
      for (int g = 0; g < 2; g++) bfr[g] = ld16s(&Bs[cur][0], wc * 32 + g * 16 + llo, ks8 + lhi);
#pragma unroll
      for (int f = 0; f < 4; f++)
#pragma unroll
        for (int g = 0; g < 2; g++) acc[f][g] = mfma16(af[f], bfr[g], acc[f][g]);
    }
    __syncthreads();
  }

#pragma unroll
  for (int fm = 0; fm < 4; fm++) {
#pragma unroll
    for (int fn = 0; fn < 2; fn++) {
      int c = n0 + wc * 32 + fn * 16 + llo;
      float bv = bias[c];
#pragma unroll
      for (int i = 0; i < 4; i++) {
        int r = m0 + wr * 64 + fm * 16 + lhi * 4 + i;
        float v = acc[fm][fn][i] + bv;
        if (resid) v += resid[(size_t)r * N + c];
        if (RELU) v = fmaxf(v, 0.0f);
        if (MODE == 0) {
          ((float*)outp)[(size_t)r * N + c] = v;
        } else if (MODE == 1) {
          ((u16*)outp)[(size_t)r * N + c] = f2bu(v);
        } else {
          int bb = r >> 10, t = r & 1023, hh = c >> 6, d = c & 63;
          ((u16*)outp)[(((size_t)(bb * NH + hh)) * TSEQ + t) * 64 + d] = f2bu(v);
        }
      }
    }
  }
}

// ---------- flash attention, swapped-QK^T, swizzled LDS, 2-phase prefetch ----------

template <bool CAUSAL>
__global__ __launch_bounds__(256) void attn_kernel(const u16* __restrict__ Qg,
                                                   const u16* __restrict__ Kg,
                                                   const u16* __restrict__ Vg,
                                                   u16* __restrict__ Og) {
  int bh = blockIdx.y;
  int b = bh >> 4, h = bh & 15;
  int q0 = blockIdx.x * 64;
  int tid = threadIdx.x, wid = tid >> 6, lane = tid & 63;
  int lhi = lane >> 4, llo = lane & 15;
  __shared__ u16 Ks[2][4096];  // [kv][d], swizzled
  __shared__ u16 Vs[2][4096];  // [d][kv], swizzled

  int qrow = q0 + wid * 16 + llo;
  const u16* qp = Qg + ((size_t)bh * TSEQ + qrow) * 64;
  s16x8 qf0 = ldfrag(qp + lhi * 4);
  s16x8 qf1 = ldfrag(qp + 32 + lhi * 4);

  f32x4 oacc[4] = {};
  float mrun = -3.0e38f, lrun = 0.0f;
  const size_t kvbase = (size_t)bh * TSEQ * 64;
  const int nt = (CAUSAL ? (q0 + 64) : TSEQ) >> 6;

  // staging maps
  const int kr = tid >> 3, kc = tid & 7;          // K: row (+0/32), chunk
  const int ksrc = (kc ^ (kr & 7)) << 3;
  const int vkv = tid & 63, vd0 = (tid >> 6) * 8; // V: kv = lane, d-chunks vd0, vd0+32
  s16x8 vr0, vr1;

  auto stageK = [&](int s0, int buf) {
    const u16* kb = Kg + kvbase + (size_t)s0 * 64;
    gload16(kb + (size_t)kr * 64 + ksrc, &Ks[buf][tid * 8]);
    gload16(kb + (size_t)(32 + kr) * 64 + ksrc, &Ks[buf][2048 + tid * 8]);
  };
  auto loadV = [&](int s0) {
    const u16* vb = Vg + kvbase + (size_t)(s0 + vkv) * 64;
    vr0 = *(const s16x8*)(vb + vd0);
    vr1 = *(const s16x8*)(vb + vd0 + 32);
  };
  auto writeV = [&](int buf) {
#pragma unroll
    for (int j = 0; j < 8; j++) {
      int d = vd0 + j;
      Vs[buf][d * 64 + ((((vkv >> 3) ^ (d & 7)) << 3) | (vkv & 7))] = (u16)vr0[j];
      int d2 = d + 32;
      Vs[buf][d2 * 64 + ((((vkv >> 3) ^ (d2 & 7)) << 3) | (vkv & 7))] = (u16)vr1[j];
    }
  };

  // prologue: tile 0
  stageK(0, 0);
  loadV(0);
  writeV(0);
  __syncthreads();

  for (int t = 0; t < nt; ++t) {
    int cur = t & 1;
    if (t + 1 < nt) {
      stageK((t + 1) * 64, cur ^ 1);
      loadV((t + 1) * 64);
    }
    int s0 = t * 64;

    // S^T = K * Q^T : sacc[g][i] = S[q=llo][kv = g*16 + lhi*4 + i]
    f32x4 sacc[4] = {};
#pragma unroll
    for (int g = 0; g < 4; g++) {
      int row = g * 16 + llo;
      sacc[g] = mfma16(ld8s(&Ks[cur][0], row, lhi * 4), qf0, sacc[g]);
      sacc[g] = mfma16(ld8s(&Ks[cur][0], row, 32 + lhi * 4), qf1, sacc[g]);
    }

    // online softmax (per-lane q = llo; partners at lane^16, lane^32)
    float sv[16];
    float pmax = -3.0e38f;
#pragma unroll
    for (int g = 0; g < 4; g++)
#pragma unroll
      for (int i = 0; i < 4; i++) {
        float sc = sacc[g][i] * 0.125f;
        if (CAUSAL) {
          int kv = s0 + g * 16 + lhi * 4 + i;
          if (kv > qrow) sc = -1.0e9f;
        }
        sv[g * 4 + i] = sc;
        pmax = fmaxf(pmax, sc);
      }
    pmax = fmaxf(pmax, __shfl_xor(pmax, 16));
    pmax = fmaxf(pmax, __shfl_xor(pmax, 32));
    float mnew = fmaxf(mrun, pmax);
    float alpha = __expf(mrun - mnew);
    float pv[16];
    float ls = 0.0f;
#pragma unroll
    for (int j = 0; j < 16; j++) {
      float p = __expf(sv[j] - mnew);
      pv[j] = p;
      ls += p;
    }
    ls += __shfl_xor(ls, 16);
    ls += __shfl_xor(ls, 32);
    lrun = lrun * alpha + ls;
    mrun = mnew;
#pragma unroll
    for (int g = 0; g < 4; g++) {
      oacc[g][0] *= alpha; oacc[g][1] *= alpha;
      oacc[g][2] *= alpha; oacc[g][3] *= alpha;
    }
    // P fragments (B-operand layout == S^T C-layout)
    s16x8 pf[2];
#pragma unroll
    for (int kk = 0; kk < 2; kk++)
#pragma unroll
      for (int i2 = 0; i2 < 8; i2++)
        pf[kk][i2] = (short)f2bu(pv[(kk * 2 + (i2 >> 2)) * 4 + (i2 & 3)]);
    // O^T += V^T * P^T
#pragma unroll
    for (int dg = 0; dg < 4; dg++) {
      int row = dg * 16 + llo;
      oacc[dg] = mfma16(ld8s(&Vs[cur][0], row, lhi * 4), pf[0], oacc[dg]);
      oacc[dg] = mfma16(ld8s(&Vs[cur][0], row, 32 + lhi * 4), pf[1], oacc[dg]);
    }

    if (t + 1 < nt) writeV(cur ^ 1);
    __syncthreads();
  }

  float inv = 1.0f / lrun;
  u16* orow = Og + (size_t)(b * TSEQ + qrow) * DMODEL + h * 64;
#pragma unroll
  for (int dg = 0; dg < 4; dg++)
#pragma unroll
    for (int i = 0; i < 4; i++)
      orow[dg * 16 + lhi * 4 + i] = f2bu(oacc[dg][i] * inv);
}

// ---------- launch ----------

extern "C" void kernel_launch(void* const* d_in, const int* in_sizes, int n_in,
                              void* d_out, int out_size, void* d_ws, size_t ws_size,
                              hipStream_t stream) {
  const float* x      = (const float*)d_in[0];
  const float* memory = (const float*)d_in[1];
  const float* sa_wq = (const float*)d_in[4];  const float* sa_bq = (const float*)d_in[5];
  const float* sa_wk = (const float*)d_in[6];  const float* sa_bk = (const float*)d_in[7];
  const float* sa_wv = (const float*)d_in[8];  const float* sa_bv = (const float*)d_in[9];
  const float* sa_wo = (const float*)d_in[10]; const float* sa_bo = (const float*)d_in[11];
  const float* ca_wq = (const float*)d_in[12]; const float* ca_bq = (const float*)d_in[13];
  const float* ca_wk = (const float*)d_in[14]; const float* ca_bk = (const float*)d_in[15];
  const float* ca_wv = (const float*)d_in[16]; const float* ca_bv = (const float*)d_in[17];
  const float* ca_wo = (const float*)d_in[18]; const float* ca_bo = (const float*)d_in[19];
  const float* ff_w1 = (const float*)d_in[20]; const float* ff_b1 = (const float*)d_in[21];
  const float* ff_w2 = (const float*)d_in[22]; const float* ff_b2 = (const float*)d_in[23];
  const float* ln1_w = (const float*)d_in[24]; const float* ln1_b = (const float*)d_in[25];
  const float* ln2_w = (const float*)d_in[26]; const float* ln2_b = (const float*)d_in[27];
  const float* ln3_w = (const float*)d_in[28]; const float* ln3_b = (const float*)d_in[29];
  float* out = (float*)d_out;

  char* ws = (char*)d_ws;
  const size_t MB = 1u << 20;
  u16* h_bf   = (u16*)(ws + 0 * MB);
  u16* mem_bf = (u16*)(ws + 8 * MB);
  u16* qb     = (u16*)(ws + 16 * MB);
  u16* kb     = (u16*)(ws + 24 * MB);
  u16* vb     = (u16*)(ws + 32 * MB);
  u16* attnb  = (u16*)(ws + 40 * MB);
  u16* ffmid  = (u16*)(ws + 48 * MB);
  u16* w_sq   = (u16*)(ws + 80 * MB);
  u16* w_sk   = (u16*)(ws + 82 * MB);
  u16* w_sv   = (u16*)(ws + 84 * MB);
  u16* w_so   = (u16*)(ws + 86 * MB);
  u16* w_cq   = (u16*)(ws + 88 * MB);
  u16* w_ck   = (u16*)(ws + 90 * MB);
  u16* w_cv   = (u16*)(ws + 92 * MB);
  u16* w_co   = (u16*)(ws + 94 * MB);
  u16* w_f1   = (u16*)(ws + 96 * MB);
  u16* w_f2   = (u16*)(ws + 104 * MB);

  f2b_kernel<<<1024, 256, 0, stream>>>(sa_wq, w_sq);
  f2b_kernel<<<1024, 256, 0, stream>>>(sa_wk, w_sk);
  f2b_kernel<<<1024, 256, 0, stream>>>(sa_wv, w_sv);
  f2b_kernel<<<1024, 256, 0, stream>>>(sa_wo, w_so);
  f2b_kernel<<<1024, 256, 0, stream>>>(ca_wq, w_cq);
  f2b_kernel<<<1024, 256, 0, stream>>>(ca_wk, w_ck);
  f2b_kernel<<<1024, 256, 0, stream>>>(ca_wv, w_cv);
  f2b_kernel<<<1024, 256, 0, stream>>>(ca_wo, w_co);
  f2b_kernel<<<4096, 256, 0, stream>>>(ff_w1, w_f1);
  f2b_kernel<<<4096, 256, 0, stream>>>(ff_w2, w_f2);
  f2b_kernel<<<4096, 256, 0, stream>>>(memory, mem_bf);

  dim3 g1024(8, 32);
  dim3 g4096(32, 32);
  dim3 gattn(16, 64);

  // ---- self-attention block ----
  ln_kernel<<<4096, 256, 0, stream>>>(x, ln1_w, ln1_b, h_bf);
  gemm_bt<2, false><<<g1024, 512, 0, stream>>>(h_bf, w_sq, sa_bq, nullptr, qb, NTOK, DMODEL, DMODEL);
  gemm_bt<2, false><<<g1024, 512, 0, stream>>>(h_bf, w_sk, sa_bk, nullptr, kb, NTOK, DMODEL, DMODEL);
  gemm_bt<2, false><<<g1024, 512, 0, stream>>>(h_bf, w_sv, sa_bv, nullptr, vb, NTOK, DMODEL, DMODEL);
  attn_kernel<true><<<gattn, 256, 0, stream>>>(qb, kb, vb, attnb);
  gemm_bt<0, false><<<g1024, 512, 0, stream>>>(attnb, w_so, sa_bo, x, out, NTOK, DMODEL, DMODEL);

  // ---- cross-attention block ----
  ln_kernel<<<4096, 256, 0, stream>>>(out, ln2_w, ln2_b, h_bf);
  gemm_bt<2, false><<<g1024, 512, 0, stream>>>(h_bf, w_cq, ca_bq, nullptr, qb, NTOK, DMODEL, DMODEL);
  gemm_bt<2, false><<<g1024, 512, 0, stream>>>(mem_bf, w_ck, ca_bk, nullptr, kb, NTOK, DMODEL, DMODEL);
  gemm_bt<2, false><<<g1024, 512, 0, stream>>>(mem_bf, w_cv, ca_bv, nullptr, vb, NTOK, DMODEL, DMODEL);
  attn_kernel<false><<<gattn, 256, 0, stream>>>(qb, kb, vb, attnb);
  gemm_bt<0, false><<<g1024, 512, 0, stream>>>(attnb, w_co, ca_bo, out, out, NTOK, DMODEL, DMODEL);

  // ---- FFN block ----
  ln_kernel<<<4096, 256, 0, stream>>>(out, ln3_w, ln3_b, h_bf);
  gemm_bt<1, true><<<g4096, 512, 0, stream>>>(h_bf, w_f1, ff_b1, nullptr, ffmid, NTOK, DFF, DMODEL);
  gemm_bt<0, false><<<g1024, 512, 0, stream>>>(ffmid, w_f2, ff_b2, out, out, NTOK, DMODEL, DFF);

  (void)in_sizes; (void)n_in; (void)out_size; (void)ws_size;
}

// Round 3
// 367.187 us; speedup vs baseline: 3.6506x; 1.1861x over previous
//
#include <hip/hip_runtime.h>
#include <hip/hip_bf16.h>

typedef unsigned short u16;
typedef __attribute__((ext_vector_type(4))) float f32x4;
typedef __attribute__((ext_vector_type(8))) short s16x8;
typedef __attribute__((ext_vector_type(4))) short s16x4;
typedef __attribute__((ext_vector_type(8))) __bf16 bf16x8;

#define NTOK 4096
#define DMODEL 1024
#define DFF 4096
#define NH 16
#define TSEQ 1024

// ---------- helpers ----------

__device__ __forceinline__ u16 f2bu(float f) {
  unsigned int u = __float_as_uint(f);
  unsigned int r = (u + 0x7FFFu + ((u >> 16) & 1u)) >> 16;
  return (u16)r;
}

__device__ __forceinline__ f32x4 mfma16(s16x8 a, s16x8 b, f32x4 c) {
  return __builtin_amdgcn_mfma_f32_16x16x32_bf16((bf16x8)a, (bf16x8)b, c, 0, 0, 0);
}

__device__ __forceinline__ void gload16(const u16* g, u16* l) {
  __builtin_amdgcn_global_load_lds(
      (const __attribute__((address_space(1))) unsigned int*)g,
      (__attribute__((address_space(3))) unsigned int*)l, 16, 0, 0);
}

// natural-layout fragment from global: 4 elems at p, 4 at p+16
__device__ __forceinline__ s16x8 ldfrag(const u16* p) {
  s16x4 lo = *(const s16x4*)p;
  s16x4 hi = *(const s16x4*)(p + 16);
  s16x8 r;
  r[0] = lo[0]; r[1] = lo[1]; r[2] = lo[2]; r[3] = lo[3];
  r[4] = hi[0]; r[5] = hi[1]; r[6] = hi[2]; r[7] = hi[3];
  return r;
}

// natural-layout fragment from a swizzled 64-elem-row LDS tile
__device__ __forceinline__ s16x8 ld8s(const u16* t, int row, int eoff) {
  int rx = row & 7;
  const u16* p1 = t + row * 64 + ((((eoff >> 3) ^ rx) << 3) | (eoff & 7));
  const u16* p2 = t + row * 64 + (((((eoff + 16) >> 3) ^ rx) << 3) | (eoff & 7));
  s16x4 lo = *(const s16x4*)p1;
  s16x4 hi = *(const s16x4*)p2;
  s16x8 r;
  r[0] = lo[0]; r[1] = lo[1]; r[2] = lo[2]; r[3] = lo[3];
  r[4] = hi[0]; r[5] = hi[1]; r[6] = hi[2]; r[7] = hi[3];
  return r;
}

// k-permuted (contiguous 16B) fragment from swizzled 64-elem-row LDS tile
__device__ __forceinline__ s16x8 ld16s(const u16* t, int row, int ch) {
  return *(const s16x8*)(t + row * 64 + ((ch ^ (row & 7)) << 3));
}

// ---------- fused fp32 -> bf16 converts (11 segments, one kernel) ----------

struct F2B {
  const float* s[11];
  u16* d[11];
};

__global__ __launch_bounds__(256) void f2b_all(F2B a) {
  int bid = blockIdx.x;
  int seg, boff;
  if (bid < 8192) { seg = bid >> 10; boff = bid & 1023; }
  else { int j = bid - 8192; seg = 8 + (j >> 12); boff = j & 4095; }
  size_t i = ((size_t)boff * 256 + threadIdx.x) * 4;
  float4 v = *(const float4*)(a.s[seg] + i);
  ushort4 o = make_ushort4(f2bu(v.x), f2bu(v.y), f2bu(v.z), f2bu(v.w));
  *(ushort4*)(a.d[seg] + i) = o;
}

// ---------- LayerNorm ----------

__global__ __launch_bounds__(256) void ln_kernel(const float* __restrict__ x,
                                                 const float* __restrict__ w,
                                                 const float* __restrict__ b,
                                                 u16* __restrict__ out) {
  int row = blockIdx.x;
  int t = threadIdx.x;
  const float* xr = x + (size_t)row * DMODEL;
  float4 v = *(const float4*)(xr + t * 4);
  float s = v.x + v.y + v.z + v.w;
#pragma unroll
  for (int off = 1; off < 64; off <<= 1) s += __shfl_xor(s, off);
  __shared__ float red[8];
  int wid = t >> 6, lane = t & 63;
  if (lane == 0) red[wid] = s;
  __syncthreads();
  float mean = (red[0] + red[1] + red[2] + red[3]) * (1.0f / 1024.0f);
  float dx = v.x - mean, dy = v.y - mean, dz = v.z - mean, dw = v.w - mean;
  float ss = dx * dx + dy * dy + dz * dz + dw * dw;
#pragma unroll
  for (int off = 1; off < 64; off <<= 1) ss += __shfl_xor(ss, off);
  if (lane == 0) red[4 + wid] = ss;
  __syncthreads();
  float sst = red[4] + red[5] + red[6] + red[7];
  float inv = 1.0f / (sqrtf(sst / 1023.0f) + 1e-6f);
  float4 wv = *(const float4*)(w + t * 4);
  float4 bv = *(const float4*)(b + t * 4);
  ushort4 o = make_ushort4(f2bu(wv.x * dx * inv + bv.x), f2bu(wv.y * dy * inv + bv.y),
                           f2bu(wv.z * dz * inv + bv.z), f2bu(wv.w * dw * inv + bv.w));
  *(ushort4*)(out + (size_t)row * DMODEL + t * 4) = o;
}

// ---------- GEMM: C[M,N] = A[M,K] * W[N,K]^T (+bias, +resid, relu) ----------
// 1D grid with XCD-chunked swizzle (nwg % 8 == 0). 512 threads, 8 waves
// (2M x 4N), 128x128 tile, BK=64, double-buffered swizzled LDS, 2-phase
// prefetch, k-permuted contiguous-16B fragments.
// MODE 0: fp32 out [M,N]; MODE 1: bf16 out [M,N];
// MODE 2: bf16 out packed [buf = c>>10][B,H,T,64], bias segment per buf.

template <int MODE, bool RELU>
__global__ __launch_bounds__(512) void gemm_bt(const u16* __restrict__ A,
                                               const u16* __restrict__ W,
                                               const float* __restrict__ b0,
                                               const float* __restrict__ b1,
                                               const float* __restrict__ b2,
                                               const float* resid, void* outp,
                                               int M, int N, int K, int gx) {
  __shared__ u16 As[2][128 * 64];
  __shared__ u16 Bs[2][128 * 64];
  const int nwg = gridDim.x;
  const int qch = nwg >> 3;
  const int bid = blockIdx.x;
  const int wg = (bid & 7) * qch + (bid >> 3);
  const int bx = wg % gx, by = wg / gx;
  const int m0 = by * 128, n0 = bx * 128;
  const int tid = threadIdx.x;
  const int wid = tid >> 6, lane = tid & 63;
  const int wr = wid >> 2, wc = wid & 3;
  const int lhi = lane >> 4, llo = lane & 15;
  f32x4 acc[4][2] = {};
  const int sr = tid >> 3, sc = tid & 7;
  const int srcoff = (sc ^ (sr & 7)) << 3;

  auto stage = [&](int kk, int buf) {
    const u16* Ap = A + (size_t)(m0 + sr) * K + kk + srcoff;
    gload16(Ap, &As[buf][tid * 8]);
    gload16(Ap + (size_t)64 * K, &As[buf][4096 + tid * 8]);
    const u16* Wp = W + (size_t)(n0 + sr) * K + kk + srcoff;
    gload16(Wp, &Bs[buf][tid * 8]);
    gload16(Wp + (size_t)64 * K, &Bs[buf][4096 + tid * 8]);
  };

  stage(0, 0);
  __syncthreads();

  for (int k0 = 0; k0 < K; k0 += 64) {
    int cur = (k0 >> 6) & 1;
    if (k0 + 64 < K) stage(k0 + 64, cur ^ 1);
#pragma unroll
    for (int ks8 = 0; ks8 < 8; ks8 += 4) {
      s16x8 af[4], bfr[2];
#pragma unroll
      for (int f = 0; f < 4; f++) af[f] = ld16s(&As[cur][0], wr * 64 + f * 16 + llo, ks8 + lhi);
#pragma unroll
      for (int g = 0; g < 2; g++) bfr[g] = ld16s(&Bs[cur][0], wc * 32 + g * 16 + llo, ks8 + lhi);
#pragma unroll
      for (int f = 0; f < 4; f++)
#pragma unroll
        for (int g = 0; g < 2; g++) acc[f][g] = mfma16(af[f], bfr[g], acc[f][g]);
    }
    __syncthreads();
  }

  const float* bias;
  if (MODE == 2) {
    int bs = n0 >> 10;
    bias = (bs == 0) ? b0 : ((bs == 1) ? b1 : b2);
  } else {
    bias = b0;
  }

#pragma unroll
  for (int fm = 0; fm < 4; fm++) {
#pragma unroll
    for (int fn = 0; fn < 2; fn++) {
      int c = n0 + wc * 32 + fn * 16 + llo;
      float bv = (MODE == 2) ? bias[c & 1023] : bias[c];
#pragma unroll
      for (int i = 0; i < 4; i++) {
        int r = m0 + wr * 64 + fm * 16 + lhi * 4 + i;
        float v = acc[fm][fn][i] + bv;
        if (resid) v += resid[(size_t)r * N + c];
        if (RELU) v = fmaxf(v, 0.0f);
        if (MODE == 0) {
          ((float*)outp)[(size_t)r * N + c] = v;
        } else if (MODE == 1) {
          ((u16*)outp)[(size_t)r * N + c] = f2bu(v);
        } else {
          int buf = c >> 10, cc = c & 1023;
          int bb = r >> 10, t = r & 1023, hh = cc >> 6, d = cc & 63;
          ((u16*)outp)[(size_t)buf * 4194304 +
                       (((size_t)(bb * NH + hh)) * TSEQ + t) * 64 + d] = f2bu(v);
        }
      }
    }
  }
}

// ---------- flash attention, swapped-QK^T, swizzled LDS, 2-phase prefetch ----------

template <bool CAUSAL>
__global__ __launch_bounds__(256) void attn_kernel(const u16* __restrict__ Qg,
                                                   const u16* __restrict__ Kg,
                                                   const u16* __restrict__ Vg,
                                                   u16* __restrict__ Og) {
  int bh = blockIdx.y;
  int b = bh >> 4, h = bh & 15;
  int q0 = blockIdx.x * 64;
  int tid = threadIdx.x, wid = tid >> 6, lane = tid & 63;
  int lhi = lane >> 4, llo = lane & 15;
  __shared__ u16 Ks[2][4096];  // [kv][d], swizzled
  __shared__ u16 Vs[2][4096];  // [d][kv], swizzled

  int qrow = q0 + wid * 16 + llo;
  const u16* qp = Qg + ((size_t)bh * TSEQ + qrow) * 64;
  s16x8 qf0 = ldfrag(qp + lhi * 4);
  s16x8 qf1 = ldfrag(qp + 32 + lhi * 4);

  f32x4 oacc[4] = {};
  float mrun = -3.0e38f, lrun = 0.0f;
  const size_t kvbase = (size_t)bh * TSEQ * 64;
  const int nt = (CAUSAL ? (q0 + 64) : TSEQ) >> 6;

  const int kr = tid >> 3, kc = tid & 7;
  const int ksrc = (kc ^ (kr & 7)) << 3;
  const int vkv = tid & 63, vd0 = (tid >> 6) * 8;
  s16x8 vr0, vr1;

  auto stageK = [&](int s0, int buf) {
    const u16* kb = Kg + kvbase + (size_t)s0 * 64;
    gload16(kb + (size_t)kr * 64 + ksrc, &Ks[buf][tid * 8]);
    gload16(kb + (size_t)(32 + kr) * 64 + ksrc, &Ks[buf][2048 + tid * 8]);
  };
  auto loadV = [&](int s0) {
    const u16* vb = Vg + kvbase + (size_t)(s0 + vkv) * 64;
    vr0 = *(const s16x8*)(vb + vd0);
    vr1 = *(const s16x8*)(vb + vd0 + 32);
  };
  auto writeV = [&](int buf) {
#pragma unroll
    for (int j = 0; j < 8; j++) {
      int d = vd0 + j;
      Vs[buf][d * 64 + ((((vkv >> 3) ^ (d & 7)) << 3) | (vkv & 7))] = (u16)vr0[j];
      int d2 = d + 32;
      Vs[buf][d2 * 64 + ((((vkv >> 3) ^ (d2 & 7)) << 3) | (vkv & 7))] = (u16)vr1[j];
    }
  };

  stageK(0, 0);
  loadV(0);
  writeV(0);
  __syncthreads();

  for (int t = 0; t < nt; ++t) {
    int cur = t & 1;
    if (t + 1 < nt) {
      stageK((t + 1) * 64, cur ^ 1);
      loadV((t + 1) * 64);
    }
    int s0 = t * 64;

    f32x4 sacc[4] = {};
#pragma unroll
    for (int g = 0; g < 4; g++) {
      int row = g * 16 + llo;
      sacc[g] = mfma16(ld8s(&Ks[cur][0], row, lhi * 4), qf0, sacc[g]);
      sacc[g] = mfma16(ld8s(&Ks[cur][0], row, 32 + lhi * 4), qf1, sacc[g]);
    }

    float sv[16];
    float pmax = -3.0e38f;
#pragma unroll
    for (int g = 0; g < 4; g++)
#pragma unroll
      for (int i = 0; i < 4; i++) {
        float sc = sacc[g][i] * 0.125f;
        if (CAUSAL) {
          int kv = s0 + g * 16 + lhi * 4 + i;
          if (kv > qrow) sc = -1.0e9f;
        }
        sv[g * 4 + i] = sc;
        pmax = fmaxf(pmax, sc);
      }
    pmax = fmaxf(pmax, __shfl_xor(pmax, 16));
    pmax = fmaxf(pmax, __shfl_xor(pmax, 32));
    float mnew = fmaxf(mrun, pmax);
    float alpha = __expf(mrun - mnew);
    float pv[16];
    float ls = 0.0f;
#pragma unroll
    for (int j = 0; j < 16; j++) {
      float p = __expf(sv[j] - mnew);
      pv[j] = p;
      ls += p;
    }
    ls += __shfl_xor(ls, 16);
    ls += __shfl_xor(ls, 32);
    lrun = lrun * alpha + ls;
    mrun = mnew;
#pragma unroll
    for (int g = 0; g < 4; g++) {
      oacc[g][0] *= alpha; oacc[g][1] *= alpha;
      oacc[g][2] *= alpha; oacc[g][3] *= alpha;
    }
    s16x8 pf[2];
#pragma unroll
    for (int kk = 0; kk < 2; kk++)
#pragma unroll
      for (int i2 = 0; i2 < 8; i2++)
        pf[kk][i2] = (short)f2bu(pv[(kk * 2 + (i2 >> 2)) * 4 + (i2 & 3)]);
#pragma unroll
    for (int dg = 0; dg < 4; dg++) {
      int row = dg * 16 + llo;
      oacc[dg] = mfma16(ld8s(&Vs[cur][0], row, lhi * 4), pf[0], oacc[dg]);
      oacc[dg] = mfma16(ld8s(&Vs[cur][0], row, 32 + lhi * 4), pf[1], oacc[dg]);
    }

    if (t + 1 < nt) writeV(cur ^ 1);
    __syncthreads();
  }

  float inv = 1.0f / lrun;
  u16* orow = Og + (size_t)(b * TSEQ + qrow) * DMODEL + h * 64;
#pragma unroll
  for (int dg = 0; dg < 4; dg++)
#pragma unroll
    for (int i = 0; i < 4; i++)
      orow[dg * 16 + lhi * 4 + i] = f2bu(oacc[dg][i] * inv);
}

// ---------- launch ----------

extern "C" void kernel_launch(void* const* d_in, const int* in_sizes, int n_in,
                              void* d_out, int out_size, void* d_ws, size_t ws_size,
                              hipStream_t stream) {
  const float* x      = (const float*)d_in[0];
  const float* memory = (const float*)d_in[1];
  const float* sa_wq = (const float*)d_in[4];  const float* sa_bq = (const float*)d_in[5];
  const float* sa_wk = (const float*)d_in[6];  const float* sa_bk = (const float*)d_in[7];
  const float* sa_wv = (const float*)d_in[8];  const float* sa_bv = (const float*)d_in[9];
  const float* sa_wo = (const float*)d_in[10]; const float* sa_bo = (const float*)d_in[11];
  const float* ca_wq = (const float*)d_in[12]; const float* ca_bq = (const float*)d_in[13];
  const float* ca_wk = (const float*)d_in[14]; const float* ca_bk = (const float*)d_in[15];
  const float* ca_wv = (const float*)d_in[16]; const float* ca_bv = (const float*)d_in[17];
  const float* ca_wo = (const float*)d_in[18]; const float* ca_bo = (const float*)d_in[19];
  const float* ff_w1 = (const float*)d_in[20]; const float* ff_b1 = (const float*)d_in[21];
  const float* ff_w2 = (const float*)d_in[22]; const float* ff_b2 = (const float*)d_in[23];
  const float* ln1_w = (const float*)d_in[24]; const float* ln1_b = (const float*)d_in[25];
  const float* ln2_w = (const float*)d_in[26]; const float* ln2_b = (const float*)d_in[27];
  const float* ln3_w = (const float*)d_in[28]; const float* ln3_b = (const float*)d_in[29];
  float* out = (float*)d_out;

  char* ws = (char*)d_ws;
  const size_t MB = 1u << 20;
  u16* h_bf   = (u16*)(ws + 0 * MB);
  u16* mem_bf = (u16*)(ws + 8 * MB);
  u16* qb     = (u16*)(ws + 16 * MB);   // qb/kb/vb contiguous, 8MB apart
  u16* kb     = (u16*)(ws + 24 * MB);
  u16* vb     = (u16*)(ws + 32 * MB);
  u16* attnb  = (u16*)(ws + 40 * MB);
  u16* ffmid  = (u16*)(ws + 48 * MB);
  u16* w_sq   = (u16*)(ws + 80 * MB);   // w_sq/w_sk/w_sv contiguous -> fused QKV W
  u16* w_sk   = (u16*)(ws + 82 * MB);
  u16* w_sv   = (u16*)(ws + 84 * MB);
  u16* w_so   = (u16*)(ws + 86 * MB);
  u16* w_cq   = (u16*)(ws + 88 * MB);
  u16* w_ck   = (u16*)(ws + 90 * MB);   // w_ck/w_cv contiguous -> fused KV W
  u16* w_cv   = (u16*)(ws + 92 * MB);
  u16* w_co   = (u16*)(ws + 94 * MB);
  u16* w_f1   = (u16*)(ws + 96 * MB);
  u16* w_f2   = (u16*)(ws + 104 * MB);

  // fused weight + memory converts
  F2B fa;
  fa.s[0] = sa_wq; fa.d[0] = w_sq;
  fa.s[1] = sa_wk; fa.d[1] = w_sk;
  fa.s[2] = sa_wv; fa.d[2] = w_sv;
  fa.s[3] = sa_wo; fa.d[3] = w_so;
  fa.s[4] = ca_wq; fa.d[4] = w_cq;
  fa.s[5] = ca_wk; fa.d[5] = w_ck;
  fa.s[6] = ca_wv; fa.d[6] = w_cv;
  fa.s[7] = ca_wo; fa.d[7] = w_co;
  fa.s[8] = ff_w1; fa.d[8] = w_f1;
  fa.s[9] = ff_w2; fa.d[9] = w_f2;
  fa.s[10] = memory; fa.d[10] = mem_bf;
  f2b_all<<<20480, 256, 0, stream>>>(fa);

  dim3 gattn(16, 64);

  // ---- self-attention block ----
  ln_kernel<<<4096, 256, 0, stream>>>(x, ln1_w, ln1_b, h_bf);
  gemm_bt<2, false><<<768, 512, 0, stream>>>(h_bf, w_sq, sa_bq, sa_bk, sa_bv,
                                             nullptr, qb, NTOK, 3072, DMODEL, 24);
  attn_kernel<true><<<gattn, 256, 0, stream>>>(qb, kb, vb, attnb);
  gemm_bt<0, false><<<256, 512, 0, stream>>>(attnb, w_so, sa_bo, nullptr, nullptr,
                                             x, out, NTOK, DMODEL, DMODEL, 8);

  // ---- cross-attention block ----
  ln_kernel<<<4096, 256, 0, stream>>>(out, ln2_w, ln2_b, h_bf);
  gemm_bt<2, false><<<256, 512, 0, stream>>>(h_bf, w_cq, ca_bq, nullptr, nullptr,
                                             nullptr, qb, NTOK, DMODEL, DMODEL, 8);
  gemm_bt<2, false><<<512, 512, 0, stream>>>(mem_bf, w_ck, ca_bk, ca_bv, nullptr,
                                             nullptr, kb, NTOK, 2048, DMODEL, 16);
  attn_kernel<false><<<gattn, 256, 0, stream>>>(qb, kb, vb, attnb);
  gemm_bt<0, false><<<256, 512, 0, stream>>>(attnb, w_co, ca_bo, nullptr, nullptr,
                                             out, out, NTOK, DMODEL, DMODEL, 8);

  // ---- FFN block ----
  ln_kernel<<<4096, 256, 0, stream>>>(out, ln3_w, ln3_b, h_bf);
  gemm_bt<1, true><<<1024, 512, 0, stream>>>(h_bf, w_f1, ff_b1, nullptr, nullptr,
                                             nullptr, ffmid, NTOK, DFF, DMODEL, 32);
  gemm_bt<0, false><<<256, 512, 0, stream>>>(ffmid, w_f2, ff_b2, nullptr, nullptr,
                                             out, out, NTOK, DMODEL, DFF, 8);

  (void)in_sizes; (void)n_in; (void)out_size; (void)ws_size;
}

// Round 4
// 353.874 us; speedup vs baseline: 3.7880x; 1.0376x over previous
//
#include <hip/hip_runtime.h>
#include <hip/hip_bf16.h>

typedef unsigned short u16;
typedef __attribute__((ext_vector_type(4))) float f32x4;
typedef __attribute__((ext_vector_type(8))) short s16x8;
typedef __attribute__((ext_vector_type(4))) short s16x4;
typedef __attribute__((ext_vector_type(8))) __bf16 bf16x8;

#define NTOK 4096
#define DMODEL 1024
#define DFF 4096
#define NH 16
#define TSEQ 1024

// ---------- helpers ----------

__device__ __forceinline__ u16 f2bu(float f) {
  unsigned int u = __float_as_uint(f);
  unsigned int r = (u + 0x7FFFu + ((u >> 16) & 1u)) >> 16;
  return (u16)r;
}

__device__ __forceinline__ f32x4 mfma16(s16x8 a, s16x8 b, f32x4 c) {
  return __builtin_amdgcn_mfma_f32_16x16x32_bf16((bf16x8)a, (bf16x8)b, c, 0, 0, 0);
}

__device__ __forceinline__ void gload16(const u16* g, u16* l) {
  __builtin_amdgcn_global_load_lds(
      (const __attribute__((address_space(1))) unsigned int*)g,
      (__attribute__((address_space(3))) unsigned int*)l, 16, 0, 0);
}

// natural-layout fragment from global: 4 elems at p, 4 at p+16
__device__ __forceinline__ s16x8 ldfrag(const u16* p) {
  s16x4 lo = *(const s16x4*)p;
  s16x4 hi = *(const s16x4*)(p + 16);
  s16x8 r;
  r[0] = lo[0]; r[1] = lo[1]; r[2] = lo[2]; r[3] = lo[3];
  r[4] = hi[0]; r[5] = hi[1]; r[6] = hi[2]; r[7] = hi[3];
  return r;
}

// natural-layout fragment from a swizzled 64-elem-row LDS tile
__device__ __forceinline__ s16x8 ld8s(const u16* t, int row, int eoff) {
  int rx = row & 7;
  const u16* p1 = t + row * 64 + ((((eoff >> 3) ^ rx) << 3) | (eoff & 7));
  const u16* p2 = t + row * 64 + (((((eoff + 16) >> 3) ^ rx) << 3) | (eoff & 7));
  s16x4 lo = *(const s16x4*)p1;
  s16x4 hi = *(const s16x4*)p2;
  s16x8 r;
  r[0] = lo[0]; r[1] = lo[1]; r[2] = lo[2]; r[3] = lo[3];
  r[4] = hi[0]; r[5] = hi[1]; r[6] = hi[2]; r[7] = hi[3];
  return r;
}

// k-permuted (contiguous 16B) fragment from swizzled 64-elem-row LDS tile
__device__ __forceinline__ s16x8 ld16s(const u16* t, int row, int ch) {
  return *(const s16x8*)(t + row * 64 + ((ch ^ (row & 7)) << 3));
}

// ---------- fused fp32 -> bf16 converts (11 segments, one kernel) ----------

struct F2B {
  const float* s[11];
  u16* d[11];
};

__global__ __launch_bounds__(256) void f2b_all(F2B a) {
  int bid = blockIdx.x;
  int seg, boff;
  if (bid < 8192) { seg = bid >> 10; boff = bid & 1023; }
  else { int j = bid - 8192; seg = 8 + (j >> 12); boff = j & 4095; }
  size_t i = ((size_t)boff * 256 + threadIdx.x) * 4;
  float4 v = *(const float4*)(a.s[seg] + i);
  ushort4 o = make_ushort4(f2bu(v.x), f2bu(v.y), f2bu(v.z), f2bu(v.w));
  *(ushort4*)(a.d[seg] + i) = o;
}

// ---------- LayerNorm ----------

__global__ __launch_bounds__(256) void ln_kernel(const float* __restrict__ x,
                                                 const float* __restrict__ w,
                                                 const float* __restrict__ b,
                                                 u16* __restrict__ out) {
  int row = blockIdx.x;
  int t = threadIdx.x;
  const float* xr = x + (size_t)row * DMODEL;
  float4 v = *(const float4*)(xr + t * 4);
  float s = v.x + v.y + v.z + v.w;
#pragma unroll
  for (int off = 1; off < 64; off <<= 1) s += __shfl_xor(s, off);
  __shared__ float red[8];
  int wid = t >> 6, lane = t & 63;
  if (lane == 0) red[wid] = s;
  __syncthreads();
  float mean = (red[0] + red[1] + red[2] + red[3]) * (1.0f / 1024.0f);
  float dx = v.x - mean, dy = v.y - mean, dz = v.z - mean, dw = v.w - mean;
  float ss = dx * dx + dy * dy + dz * dz + dw * dw;
#pragma unroll
  for (int off = 1; off < 64; off <<= 1) ss += __shfl_xor(ss, off);
  if (lane == 0) red[4 + wid] = ss;
  __syncthreads();
  float sst = red[4] + red[5] + red[6] + red[7];
  float inv = 1.0f / (sqrtf(sst / 1023.0f) + 1e-6f);
  float4 wv = *(const float4*)(w + t * 4);
  float4 bv = *(const float4*)(b + t * 4);
  ushort4 o = make_ushort4(f2bu(wv.x * dx * inv + bv.x), f2bu(wv.y * dy * inv + bv.y),
                           f2bu(wv.z * dz * inv + bv.z), f2bu(wv.w * dw * inv + bv.w));
  *(ushort4*)(out + (size_t)row * DMODEL + t * 4) = o;
}

// ---------- GEMM: C[M,N] = A[M,K] * W[N,K]^T (+bias, +resid, relu) ----------
// 1D grid, XCD-chunked swizzle (nwg % 8 == 0). 512 threads, 8 waves (2M x 4N),
// 128x128 tile, BK=64, double-buffered swizzled LDS, 2-phase prefetch,
// k-permuted contiguous-16B fragments. ld = row stride of A and W.
// MODE 0: fp32 out [M,N] (bias optional); MODE 1: bf16 out [M,N];
// MODE 2: bf16 out packed [buf = c>>10][B,H,T,64], bias segment per buf.
// SPLITK: adjacent swizzled block pairs take K-halves of the same tile;
// half h writes fp32 partial at outp + h*M*N (no bias/resid).

template <int MODE, bool RELU, bool SPLITK = false>
__global__ __launch_bounds__(512) void gemm_bt(const u16* __restrict__ A,
                                               const u16* __restrict__ W,
                                               const float* __restrict__ b0,
                                               const float* __restrict__ b1,
                                               const float* __restrict__ b2,
                                               const float* resid, void* outp,
                                               int M, int N, int K, int ld,
                                               int gx) {
  __shared__ u16 As[2][128 * 64];
  __shared__ u16 Bs[2][128 * 64];
  const int nwg = gridDim.x;
  const int qch = nwg >> 3;
  const int bid = blockIdx.x;
  int wg = (bid & 7) * qch + (bid >> 3);
  int half = 0;
  if (SPLITK) { half = wg & 1; wg >>= 1; }
  const int bx = wg % gx, by = wg / gx;
  const int m0 = by * 128, n0 = bx * 128;
  if (SPLITK) { A += (size_t)half * K; W += (size_t)half * K; }
  const int tid = threadIdx.x;
  const int wid = tid >> 6, lane = tid & 63;
  const int wr = wid >> 2, wc = wid & 3;
  const int lhi = lane >> 4, llo = lane & 15;
  f32x4 acc[4][2] = {};
  const int sr = tid >> 3, sc = tid & 7;
  const int srcoff = (sc ^ (sr & 7)) << 3;

  auto stage = [&](int kk, int buf) {
    const u16* Ap = A + (size_t)(m0 + sr) * ld + kk + srcoff;
    gload16(Ap, &As[buf][tid * 8]);
    gload16(Ap + (size_t)64 * ld, &As[buf][4096 + tid * 8]);
    const u16* Wp = W + (size_t)(n0 + sr) * ld + kk + srcoff;
    gload16(Wp, &Bs[buf][tid * 8]);
    gload16(Wp + (size_t)64 * ld, &Bs[buf][4096 + tid * 8]);
  };

  stage(0, 0);
  __syncthreads();

  for (int k0 = 0; k0 < K; k0 += 64) {
    int cur = (k0 >> 6) & 1;
    if (k0 + 64 < K) stage(k0 + 64, cur ^ 1);
#pragma unroll
    for (int ks8 = 0; ks8 < 8; ks8 += 4) {
      s16x8 af[4], bfr[2];
#pragma unroll
      for (int f = 0; f < 4; f++) af[f] = ld16s(&As[cur][0], wr * 64 + f * 16 + llo, ks8 + lhi);
#pragma unroll
      for (int g = 0; g < 2; g++) bfr[g] = ld16s(&Bs[cur][0], wc * 32 + g * 16 + llo, ks8 + lhi);
#pragma unroll
      for (int f = 0; f < 4; f++)
#pragma unroll
        for (int g = 0; g < 2; g++) acc[f][g] = mfma16(af[f], bfr[g], acc[f][g]);
    }
    __syncthreads();
  }

  const float* bias;
  if (MODE == 2) {
    int bs = n0 >> 10;
    bias = (bs == 0) ? b0 : ((bs == 1) ? b1 : b2);
  } else {
    bias = b0;
  }

#pragma unroll
  for (int fm = 0; fm < 4; fm++) {
#pragma unroll
    for (int fn = 0; fn < 2; fn++) {
      int c = n0 + wc * 32 + fn * 16 + llo;
      float bv = bias ? (MODE == 2 ? bias[c & 1023] : bias[c]) : 0.0f;
#pragma unroll
      for (int i = 0; i < 4; i++) {
        int r = m0 + wr * 64 + fm * 16 + lhi * 4 + i;
        float v = acc[fm][fn][i] + bv;
        if (resid) v += resid[(size_t)r * N + c];
        if (RELU) v = fmaxf(v, 0.0f);
        if (MODE == 0) {
          ((float*)outp)[(size_t)half * M * N + (size_t)r * N + c] = v;
        } else if (MODE == 1) {
          ((u16*)outp)[(size_t)r * N + c] = f2bu(v);
        } else {
          int buf = c >> 10, cc = c & 1023;
          int bb = r >> 10, t = r & 1023, hh = cc >> 6, d = cc & 63;
          ((u16*)outp)[(size_t)buf * 4194304 +
                       (((size_t)(bb * NH + hh)) * TSEQ + t) * 64 + d] = f2bu(v);
        }
      }
    }
  }
}

// ---------- split-K reduce: out = p0 + p1 + bias + out ----------

__global__ __launch_bounds__(256) void ff2_reduce(const float* __restrict__ p,
                                                  const float* __restrict__ bias,
                                                  float* __restrict__ out) {
  int row = blockIdx.x, t = threadIdx.x;
  size_t i = (size_t)row * 1024 + t * 4;
  const float* p1 = p + (size_t)4194304;
  float4 a = *(const float4*)(p + i);
  float4 b = *(const float4*)(p1 + i);
  float4 r = *(const float4*)(out + i);
  float4 bv = *(const float4*)(bias + t * 4);
  float4 o = make_float4(a.x + b.x + r.x + bv.x, a.y + b.y + r.y + bv.y,
                         a.z + b.z + r.z + bv.z, a.w + b.w + r.w + bv.w);
  *(float4*)(out + i) = o;
}

// ---------- flash attention, swapped-QK^T, QBLK=128 (2 strips/wave) ----------

template <bool CAUSAL>
__global__ __launch_bounds__(256) void attn_kernel(const u16* __restrict__ Qg,
                                                   const u16* __restrict__ Kg,
                                                   const u16* __restrict__ Vg,
                                                   u16* __restrict__ Og) {
  int bh = blockIdx.y;
  int b = bh >> 4, h = bh & 15;
  int q0 = blockIdx.x * 128;
  int tid = threadIdx.x, wid = tid >> 6, lane = tid & 63;
  int lhi = lane >> 4, llo = lane & 15;
  __shared__ u16 Ks[2][4096];  // [kv][d], swizzled
  __shared__ u16 Vs[2][4096];  // [d][kv], swizzled

  int qr = q0 + wid * 16 + llo;  // strip 0 row; strip 1 at +64
  const u16* qp0 = Qg + ((size_t)bh * TSEQ + qr) * 64;
  const u16* qp1 = qp0 + 64 * 64;
  s16x8 qf[2][2];
  qf[0][0] = ldfrag(qp0 + lhi * 4);
  qf[0][1] = ldfrag(qp0 + 32 + lhi * 4);
  qf[1][0] = ldfrag(qp1 + lhi * 4);
  qf[1][1] = ldfrag(qp1 + 32 + lhi * 4);

  f32x4 oacc[2][4] = {};
  float mrun[2] = {-3.0e38f, -3.0e38f}, lrun[2] = {0.0f, 0.0f};
  const size_t kvbase = (size_t)bh * TSEQ * 64;
  const int nt = (CAUSAL ? (q0 + 128) : TSEQ) >> 6;

  const int kr = tid >> 3, kc = tid & 7;
  const int ksrc = (kc ^ (kr & 7)) << 3;
  const int vkv = tid & 63, vd0 = (tid >> 6) * 8;
  s16x8 vr0, vr1;

  auto stageK = [&](int s0, int buf) {
    const u16* kb = Kg + kvbase + (size_t)s0 * 64;
    gload16(kb + (size_t)kr * 64 + ksrc, &Ks[buf][tid * 8]);
    gload16(kb + (size_t)(32 + kr) * 64 + ksrc, &Ks[buf][2048 + tid * 8]);
  };
  auto loadV = [&](int s0) {
    const u16* vb = Vg + kvbase + (size_t)(s0 + vkv) * 64;
    vr0 = *(const s16x8*)(vb + vd0);
    vr1 = *(const s16x8*)(vb + vd0 + 32);
  };
  auto writeV = [&](int buf) {
#pragma unroll
    for (int j = 0; j < 8; j++) {
      int d = vd0 + j;
      Vs[buf][d * 64 + ((((vkv >> 3) ^ (d & 7)) << 3) | (vkv & 7))] = (u16)vr0[j];
      int d2 = d + 32;
      Vs[buf][d2 * 64 + ((((vkv >> 3) ^ (d2 & 7)) << 3) | (vkv & 7))] = (u16)vr1[j];
    }
  };

  stageK(0, 0);
  loadV(0);
  writeV(0);
  __syncthreads();

  for (int t = 0; t < nt; ++t) {
    int cur = t & 1;
    if (t + 1 < nt) {
      stageK((t + 1) * 64, cur ^ 1);
      loadV((t + 1) * 64);
    }
    int s0 = t * 64;
    // strip 0 skips its fully-masked tiles (block-uniform predicate)
    const bool act0 = !CAUSAL || (s0 < q0 + 64);

    // K fragments loaded once, shared by both strips
    s16x8 kf[4][2];
#pragma unroll
    for (int g = 0; g < 4; g++) {
      int row = g * 16 + llo;
      kf[g][0] = ld8s(&Ks[cur][0], row, lhi * 4);
      kf[g][1] = ld8s(&Ks[cur][0], row, 32 + lhi * 4);
    }

    s16x8 pf[2][2];
#pragma unroll
    for (int s = 0; s < 2; s++) {
      if (s == 0 && !act0) continue;
      f32x4 sacc[4] = {};
#pragma unroll
      for (int g = 0; g < 4; g++) {
        sacc[g] = mfma16(kf[g][0], qf[s][0], sacc[g]);
        sacc[g] = mfma16(kf[g][1], qf[s][1], sacc[g]);
      }
      int qrow = qr + s * 64;
      float sv[16];
      float pmax = -3.0e38f;
#pragma unroll
      for (int g = 0; g < 4; g++)
#pragma unroll
        for (int i = 0; i < 4; i++) {
          float sc = sacc[g][i] * 0.125f;
          if (CAUSAL) {
            int kv = s0 + g * 16 + lhi * 4 + i;
            if (kv > qrow) sc = -1.0e9f;
          }
          sv[g * 4 + i] = sc;
          pmax = fmaxf(pmax, sc);
        }
      pmax = fmaxf(pmax, __shfl_xor(pmax, 16));
      pmax = fmaxf(pmax, __shfl_xor(pmax, 32));
      float mnew = fmaxf(mrun[s], pmax);
      float alpha = __expf(mrun[s] - mnew);
      float ls = 0.0f;
#pragma unroll
      for (int j = 0; j < 16; j++) {
        float p = __expf(sv[j] - mnew);
        sv[j] = p;
        ls += p;
      }
      ls += __shfl_xor(ls, 16);
      ls += __shfl_xor(ls, 32);
      lrun[s] = lrun[s] * alpha + ls;
      mrun[s] = mnew;
#pragma unroll
      for (int g = 0; g < 4; g++) {
        oacc[s][g][0] *= alpha; oacc[s][g][1] *= alpha;
        oacc[s][g][2] *= alpha; oacc[s][g][3] *= alpha;
      }
#pragma unroll
      for (int kk = 0; kk < 2; kk++)
#pragma unroll
        for (int i2 = 0; i2 < 8; i2++)
          pf[s][kk][i2] = (short)f2bu(sv[(kk * 2 + (i2 >> 2)) * 4 + (i2 & 3)]);
    }

    // V fragments loaded once, shared by both strips
#pragma unroll
    for (int dg = 0; dg < 4; dg++) {
      int row = dg * 16 + llo;
      s16x8 vf0 = ld8s(&Vs[cur][0], row, lhi * 4);
      s16x8 vf1 = ld8s(&Vs[cur][0], row, 32 + lhi * 4);
#pragma unroll
      for (int s = 0; s < 2; s++) {
        if (s == 0 && !act0) continue;
        oacc[s][dg] = mfma16(vf0, pf[s][0], oacc[s][dg]);
        oacc[s][dg] = mfma16(vf1, pf[s][1], oacc[s][dg]);
      }
    }

    if (t + 1 < nt) writeV(cur ^ 1);
    __syncthreads();
  }

#pragma unroll
  for (int s = 0; s < 2; s++) {
    float inv = 1.0f / lrun[s];
    u16* orow = Og + (size_t)(b * TSEQ + qr + s * 64) * DMODEL + h * 64;
#pragma unroll
    for (int dg = 0; dg < 4; dg++)
#pragma unroll
      for (int i = 0; i < 4; i++)
        orow[dg * 16 + lhi * 4 + i] = f2bu(oacc[s][dg][i] * inv);
  }
}

// ---------- launch ----------

extern "C" void kernel_launch(void* const* d_in, const int* in_sizes, int n_in,
                              void* d_out, int out_size, void* d_ws, size_t ws_size,
                              hipStream_t stream) {
  const float* x      = (const float*)d_in[0];
  const float* memory = (const float*)d_in[1];
  const float* sa_wq = (const float*)d_in[4];  const float* sa_bq = (const float*)d_in[5];
  const float* sa_wk = (const float*)d_in[6];  const float* sa_bk = (const float*)d_in[7];
  const float* sa_wv = (const float*)d_in[8];  const float* sa_bv = (const float*)d_in[9];
  const float* sa_wo = (const float*)d_in[10]; const float* sa_bo = (const float*)d_in[11];
  const float* ca_wq = (const float*)d_in[12]; const float* ca_bq = (const float*)d_in[13];
  const float* ca_wk = (const float*)d_in[14]; const float* ca_bk = (const float*)d_in[15];
  const float* ca_wv = (const float*)d_in[16]; const float* ca_bv = (const float*)d_in[17];
  const float* ca_wo = (const float*)d_in[18]; const float* ca_bo = (const float*)d_in[19];
  const float* ff_w1 = (const float*)d_in[20]; const float* ff_b1 = (const float*)d_in[21];
  const float* ff_w2 = (const float*)d_in[22]; const float* ff_b2 = (const float*)d_in[23];
  const float* ln1_w = (const float*)d_in[24]; const float* ln1_b = (const float*)d_in[25];
  const float* ln2_w = (const float*)d_in[26]; const float* ln2_b = (const float*)d_in[27];
  const float* ln3_w = (const float*)d_in[28]; const float* ln3_b = (const float*)d_in[29];
  float* out = (float*)d_out;

  char* ws = (char*)d_ws;
  const size_t MB = 1u << 20;
  u16* h_bf   = (u16*)(ws + 0 * MB);
  u16* mem_bf = (u16*)(ws + 8 * MB);
  u16* qb     = (u16*)(ws + 16 * MB);   // qb/kb/vb contiguous, 8MB apart
  u16* kb     = (u16*)(ws + 24 * MB);
  u16* vb     = (u16*)(ws + 32 * MB);
  u16* attnb  = (u16*)(ws + 40 * MB);
  u16* ffmid  = (u16*)(ws + 48 * MB);
  float* pk   = (float*)(ws + 16 * MB); // split-K partials (reuse qb..attnb, 32MB)
  u16* w_sq   = (u16*)(ws + 80 * MB);   // w_sq/w_sk/w_sv contiguous
  u16* w_sk   = (u16*)(ws + 82 * MB);
  u16* w_sv   = (u16*)(ws + 84 * MB);
  u16* w_so   = (u16*)(ws + 86 * MB);
  u16* w_cq   = (u16*)(ws + 88 * MB);
  u16* w_ck   = (u16*)(ws + 90 * MB);   // w_ck/w_cv contiguous
  u16* w_cv   = (u16*)(ws + 92 * MB);
  u16* w_co   = (u16*)(ws + 94 * MB);
  u16* w_f1   = (u16*)(ws + 96 * MB);
  u16* w_f2   = (u16*)(ws + 104 * MB);

  F2B fa;
  fa.s[0] = sa_wq; fa.d[0] = w_sq;
  fa.s[1] = sa_wk; fa.d[1] = w_sk;
  fa.s[2] = sa_wv; fa.d[2] = w_sv;
  fa.s[3] = sa_wo; fa.d[3] = w_so;
  fa.s[4] = ca_wq; fa.d[4] = w_cq;
  fa.s[5] = ca_wk; fa.d[5] = w_ck;
  fa.s[6] = ca_wv; fa.d[6] = w_cv;
  fa.s[7] = ca_wo; fa.d[7] = w_co;
  fa.s[8] = ff_w1; fa.d[8] = w_f1;
  fa.s[9] = ff_w2; fa.d[9] = w_f2;
  fa.s[10] = memory; fa.d[10] = mem_bf;
  f2b_all<<<20480, 256, 0, stream>>>(fa);

  dim3 gattn(8, 64);

  // ---- self-attention block ----
  ln_kernel<<<4096, 256, 0, stream>>>(x, ln1_w, ln1_b, h_bf);
  gemm_bt<2, false><<<768, 512, 0, stream>>>(h_bf, w_sq, sa_bq, sa_bk, sa_bv,
                                             nullptr, qb, NTOK, 3072, DMODEL, DMODEL, 24);
  attn_kernel<true><<<gattn, 256, 0, stream>>>(qb, kb, vb, attnb);
  gemm_bt<0, false><<<256, 512, 0, stream>>>(attnb, w_so, sa_bo, nullptr, nullptr,
                                             x, out, NTOK, DMODEL, DMODEL, DMODEL, 8);

  // ---- cross-attention block ----
  ln_kernel<<<4096, 256, 0, stream>>>(out, ln2_w, ln2_b, h_bf);
  gemm_bt<2, false><<<256, 512, 0, stream>>>(h_bf, w_cq, ca_bq, nullptr, nullptr,
                                             nullptr, qb, NTOK, DMODEL, DMODEL, DMODEL, 8);
  gemm_bt<2, false><<<512, 512, 0, stream>>>(mem_bf, w_ck, ca_bk, ca_bv, nullptr,
                                             nullptr, kb, NTOK, 2048, DMODEL, DMODEL, 16);
  attn_kernel<false><<<gattn, 256, 0, stream>>>(qb, kb, vb, attnb);
  gemm_bt<0, false><<<256, 512, 0, stream>>>(attnb, w_co, ca_bo, nullptr, nullptr,
                                             out, out, NTOK, DMODEL, DMODEL, DMODEL, 8);

  // ---- FFN block ----
  ln_kernel<<<4096, 256, 0, stream>>>(out, ln3_w, ln3_b, h_bf);
  gemm_bt<1, true><<<1024, 512, 0, stream>>>(h_bf, w_f1, ff_b1, nullptr, nullptr,
                                             nullptr, ffmid, NTOK, DFF, DMODEL, DMODEL, 32);
  gemm_bt<0, false, true><<<512, 512, 0, stream>>>(ffmid, w_f2, nullptr, nullptr, nullptr,
                                                   nullptr, pk, NTOK, DMODEL, 2048, DFF, 8);
  ff2_reduce<<<4096, 256, 0, stream>>>(pk, ff_b2, out);

  (void)in_sizes; (void)n_in; (void)out_size; (void)ws_size;
}